// Round 8
// baseline (94.771 us; speedup 1.0000x reference)
//
#include <hip/hip_runtime.h>
#include <hip/hip_bf16.h>

#define BATCH    512
#define IN_WIDTH 4096
#define OUT_F    4096
#define FAN_IN   128
#define BCHUNK   4                  // batches per LDS-resident slice (8 B rows)
#define NBG      (BATCH / BCHUNK)   // 128
#define OBLK     512                // o-range per gather block (1 lane per o)
#define NOG      (OUT_F / OBLK)     // 8

typedef float    v2f __attribute__((ext_vector_type(2)));
typedef uint32_t v2u __attribute__((ext_vector_type(2)));
typedef uint32_t v4u __attribute__((ext_vector_type(4)));

// ---------------------------------------------------------------------------
// Kernel A: input[b][j] f32 -> inTg[b/4][j][4] bf16 (8 B rows, chunk-major).
// 32x32 LDS tile; writes are packed uint2 (full 8 B row) -> coalesced.
// ---------------------------------------------------------------------------
__global__ __launch_bounds__(256) void k_transpose_in(const float* __restrict__ in,
                                                      uint16_t* __restrict__ inTg) {
  __shared__ float tile[32][33];
  const int jt = blockIdx.x * 32;
  const int bt = blockIdx.y * 32;
  const int t  = threadIdx.x;       // 0..255
  const int tx = t & 31;            // j_local
  const int ty = t >> 5;            // 0..7
#pragma unroll
  for (int r = 0; r < 32; r += 8) {
    tile[ty + r][tx] = in[(size_t)(bt + ty + r) * IN_WIDTH + (jt + tx)];
  }
  __syncthreads();
  // one 8 B row (4 batches) per thread: j = jt + (t&31), bgrp = t>>5 (0..7)
  const int jl   = t & 31;
  const int bgrp = t >> 5;
  uint32_t d[2];
#pragma unroll
  for (int h = 0; h < 2; ++h) {
    __hip_bfloat16 h0 = __float2bfloat16(tile[bgrp * 4 + 2 * h][jl]);
    __hip_bfloat16 h1 = __float2bfloat16(tile[bgrp * 4 + 2 * h + 1][jl]);
    d[h] = (uint32_t)(*reinterpret_cast<uint16_t*>(&h0)) |
           ((uint32_t)(*reinterpret_cast<uint16_t*>(&h1)) << 16);
  }
  uint2* dst = reinterpret_cast<uint2*>(inTg);
  dst[((size_t)((bt >> 2) + bgrp)) * IN_WIDTH + (jt + jl)] = make_uint2(d[0], d[1]);
}

// ---------------------------------------------------------------------------
// Kernel P: pack idx+weight -> pk[o][f] = {j, bits(w)}
// ---------------------------------------------------------------------------
__global__ __launch_bounds__(256) void k_pack(const int* __restrict__ idx,
                                              const float* __restrict__ weight,
                                              uint2* __restrict__ pk) {
  const int i = blockIdx.x * 256 + threadIdx.x;
  uint2 e;
  e.x = (uint32_t)idx[i];
  e.y = __float_as_uint(weight[i]);
  pk[i] = e;
}

// ---------------------------------------------------------------------------
// Kernel B: LDS-staged gather at 8 waves/SIMD.
// Block (og, bg): stage 32 KB slice (4096 rows x 4 batches bf16); each of 512
// lanes owns one o: 128 ds_read_b64 row gathers, depth-4 pipeline with
// counted lgkmcnt(4); 3-slot rotating pk prefetch (distance 2 steps).
// 1024 blocks -> 4 blocks/CU -> 32 waves/CU.
// ---------------------------------------------------------------------------
__global__ __launch_bounds__(512, 8) void k_gather_lds(const uint16_t* __restrict__ inTg,
                                                       const uint2* __restrict__ pk,
                                                       const float* __restrict__ bias,
                                                       float* __restrict__ out) {
  extern __shared__ char lds[];
  const int og = blockIdx.x;
  const int bg = blockIdx.y;
  const int t  = threadIdx.x;

  // ---- stage 32 KB, contiguous ----
  {
    const v4u* __restrict__ src =
        reinterpret_cast<const v4u*>(inTg + (size_t)bg * IN_WIDTH * BCHUNK);
    v4u* dst = reinterpret_cast<v4u*>(lds);
#pragma unroll
    for (int i = 0; i < 4; ++i) dst[i * 512 + t] = src[i * 512 + t];
  }
  __syncthreads();

  const int o = og * OBLK + t;            // one o per lane
  const uint32_t sb = (uint32_t)(size_t)lds;

  const uint4* __restrict__ pko =
      reinterpret_cast<const uint4*>(pk + (size_t)o * FAN_IN);   // 64 entries

  v2f a0 = {0.f, 0.f}, a1 = {0.f, 0.f};

#define DSREAD(d, jj) \
  asm volatile("ds_read_b64 %0, %1" : "=v"(d) : "v"(sb + ((jj) << 3)))

#define WAIT4() do { asm volatile("s_waitcnt lgkmcnt(4)" ::: "memory"); \
                     __builtin_amdgcn_sched_barrier(0); } while (0)
#define WAIT0() do { asm volatile("s_waitcnt lgkmcnt(0)" ::: "memory"); \
                     __builtin_amdgcn_sched_barrier(0); } while (0)

#define CONSUME(v, wbits)                                              \
  do {                                                                 \
    const float wf_ = __uint_as_float(wbits);                          \
    v2f w2_; w2_[0] = wf_; w2_[1] = wf_;                               \
    v2f x0_, x1_;                                                      \
    x0_[0] = __uint_as_float((v)[0] << 16);                            \
    x0_[1] = __uint_as_float((v)[0] & 0xffff0000u);                    \
    x1_[0] = __uint_as_float((v)[1] << 16);                            \
    x1_[1] = __uint_as_float((v)[1] & 0xffff0000u);                    \
    a0 += x0_ * w2_; a1 += x1_ * w2_;                                  \
  } while (0)

  // group g = 2 uint4 pk entries = 4 f-steps; 32 groups. 3 q-slots, slot s
  // holds group g with g%3==s. STEP(c): issue g(c+1) from slot (c+1)%3 into
  // the idle buffer; WAIT4; consume g(c) (weights direct from slot c%3);
  // refill slot c%3 <- g(c+3).
  uint4 q0a = pko[0], q0b = pko[1];   // g0
  uint4 q1a = pko[2], q1b = pko[3];   // g1
  uint4 q2a = pko[4], q2b = pko[5];   // g2

  v2u A0, A1, A2, A3, B0, B1, B2, B3;

  // prologue: issue g0 into A
  DSREAD(A0, q0a.x); DSREAD(A1, q0a.z); DSREAD(A2, q0b.x); DSREAD(A3, q0b.z);

#define STEP(Cc, QIa, QIb, QCa, QCb, VC0, VC1, VC2, VC3, VI0, VI1, VI2, VI3) \
  do {                                                                 \
    DSREAD(VI0, QIa.x); DSREAD(VI1, QIa.z);                            \
    DSREAD(VI2, QIb.x); DSREAD(VI3, QIb.z);                            \
    WAIT4();                                                           \
    CONSUME(VC0, QCa.y); CONSUME(VC1, QCa.w);                          \
    CONSUME(VC2, QCb.y); CONSUME(VC3, QCb.w);                          \
    {                                                                  \
      const int gn_ = ((Cc) + 3 > 31) ? 31 : ((Cc) + 3);               \
      QCa = pko[2 * gn_];                                              \
      QCb = pko[2 * gn_ + 1];                                          \
    }                                                                  \
  } while (0)

#pragma unroll 1
  for (int cb = 0; cb < 30; cb += 6) {
    STEP(cb + 0, q1a, q1b, q0a, q0b, A0, A1, A2, A3, B0, B1, B2, B3);
    STEP(cb + 1, q2a, q2b, q1a, q1b, B0, B1, B2, B3, A0, A1, A2, A3);
    STEP(cb + 2, q0a, q0b, q2a, q2b, A0, A1, A2, A3, B0, B1, B2, B3);
    STEP(cb + 3, q1a, q1b, q0a, q0b, B0, B1, B2, B3, A0, A1, A2, A3);
    STEP(cb + 4, q2a, q2b, q1a, q1b, A0, A1, A2, A3, B0, B1, B2, B3);
    STEP(cb + 5, q0a, q0b, q2a, q2b, B0, B1, B2, B3, A0, A1, A2, A3);
  }
  // c=30: issue g31 (slot 1) into B; consume g30 (slot 0)
  STEP(30, q1a, q1b, q0a, q0b, A0, A1, A2, A3, B0, B1, B2, B3);
  WAIT0();
  CONSUME(B0, q1a.y); CONSUME(B1, q1a.w); CONSUME(B2, q1b.y); CONSUME(B3, q1b.w);

  const float bz = bias[o];
  const float r[4] = {a0[0], a0[1], a1[0], a1[1]};
  // out[b][o], b = bg*4 + i ; lanes have consecutive o -> 256 B per store
  const size_t obase = (size_t)bg * BCHUNK * OUT_F + o;
#pragma unroll
  for (int i = 0; i < 4; ++i) out[obase + (size_t)i * OUT_F] = r[i] + bz;

#undef STEP
#undef CONSUME
#undef WAIT4
#undef WAIT0
#undef DSREAD
}

extern "C" void kernel_launch(void* const* d_in, const int* in_sizes, int n_in,
                              void* d_out, int out_size, void* d_ws, size_t ws_size,
                              hipStream_t stream) {
  const float* input  = (const float*)d_in[0];   // [512][4096] f32
  const float* weight = (const float*)d_in[1];   // [4096][128] f32
  const float* bias   = (const float*)d_in[2];   // [4096]      f32
  const int*   idx    = (const int*)d_in[3];     // [4096][128] int32
  float* out = (float*)d_out;                    // [512][4096] f32

  // ws: inTg (bf16, 4 MB) | pk (uint2, 4 MB)
  uint16_t* inTg = (uint16_t*)d_ws;
  uint2*    pk   = (uint2*)((char*)d_ws + 4u * 1024 * 1024);

  k_transpose_in<<<dim3(IN_WIDTH / 32, BATCH / 32), dim3(256), 0, stream>>>(input, inTg);
  k_pack<<<dim3(OUT_F * FAN_IN / 256), dim3(256), 0, stream>>>(idx, weight, pk);
  k_gather_lds<<<dim3(NOG, NBG), dim3(512), IN_WIDTH * BCHUNK * 2, stream>>>(
      inTg, pk, bias, out);
}

// Round 9
// 72.793 us; speedup vs baseline: 1.3019x; 1.3019x over previous
//
#include <hip/hip_runtime.h>
#include <hip/hip_bf16.h>

#define BATCH    512
#define IN_WIDTH 4096
#define OUT_F    4096
#define FAN_IN   128
#define BCHUNK   16                 // batches per slice
#define NBG      (BATCH / BCHUNK)   // 32
#define OBLK     512                // o-range per gather block
#define NOG      (OUT_F / OBLK)     // 8
#define WL       7                  // waves 0..WL-1 = LDS leg; rest = L2 leg

typedef float    v2f __attribute__((ext_vector_type(2)));
typedef uint32_t v4u __attribute__((ext_vector_type(4)));

// ---------------------------------------------------------------------------
// Kernel A: input[b][j] f32 -> inTg[b/16][j][16] bf16 (chunk-major, 32B rows)
// ---------------------------------------------------------------------------
__global__ __launch_bounds__(256) void k_transpose_in(const float* __restrict__ in,
                                                      uint16_t* __restrict__ inTg) {
  __shared__ float tile[32][33];
  const int jt = blockIdx.x * 32;
  const int bt = blockIdx.y * 32;
  const int tx = threadIdx.x;       // 0..31
  const int ty = threadIdx.y;       // 0..7
#pragma unroll
  for (int r = 0; r < 32; r += 8) {
    tile[ty + r][tx] = in[(size_t)(bt + ty + r) * IN_WIDTH + (jt + tx)];
  }
  __syncthreads();
#pragma unroll
  for (int r = 0; r < 32; r += 8) {
    const int b = bt + tx;
    const int j = jt + ty + r;
    __hip_bfloat16 hv = __float2bfloat16(tile[tx][ty + r]);
    inTg[((size_t)(b >> 4) * IN_WIDTH + j) * BCHUNK + (b & 15)] =
        *reinterpret_cast<const uint16_t*>(&hv);
  }
}

// ---------------------------------------------------------------------------
// Kernel P: pack idx+weight -> pk[o][f] = {j, bits(w)}
// ---------------------------------------------------------------------------
__global__ __launch_bounds__(256) void k_pack(const int* __restrict__ idx,
                                              const float* __restrict__ weight,
                                              uint2* __restrict__ pk) {
  const int i = blockIdx.x * 256 + threadIdx.x;
  uint2 e;
  e.x = (uint32_t)idx[i];
  e.y = __float_as_uint(weight[i]);
  pk[i] = e;
}

// consume one 16B row-half (8 bf16 batches) into a0..a3 (in scope)
#define CONSUME(v, wbits)                                              \
  do {                                                                 \
    const float wf_ = __uint_as_float(wbits);                          \
    v2f w2_; w2_[0] = wf_; w2_[1] = wf_;                               \
    v2f x0_, x1_, x2_, x3_;                                            \
    x0_[0] = __uint_as_float((v).x << 16);                             \
    x0_[1] = __uint_as_float((v).x & 0xffff0000u);                     \
    x1_[0] = __uint_as_float((v).y << 16);                             \
    x1_[1] = __uint_as_float((v).y & 0xffff0000u);                     \
    x2_[0] = __uint_as_float((v).z << 16);                             \
    x2_[1] = __uint_as_float((v).z & 0xffff0000u);                     \
    x3_[0] = __uint_as_float((v).w << 16);                             \
    x3_[1] = __uint_as_float((v).w & 0xffff0000u);                     \
    a0 += x0_ * w2_; a1 += x1_ * w2_; a2 += x2_ * w2_; a3 += x3_ * w2_;\
  } while (0)

// ---------------------------------------------------------------------------
// Kernel B: hybrid gather. All 16 waves stage the 128 KB bg-slice; then
// waves 0..WL-1 serve their o's from LDS (R7 depth-4 counted-lgkmcnt
// pipeline), waves WL..15 serve theirs from L2 (global uint4 reads of the
// same slice). Two independent memory pipes on one CU.
// ---------------------------------------------------------------------------
__global__ __launch_bounds__(1024, 4) void k_gather_hyb(const uint16_t* __restrict__ inTg,
                                                        const uint2* __restrict__ pk,
                                                        const float* __restrict__ bias,
                                                        float* __restrict__ out) {
  extern __shared__ char lds[];
  const int og = blockIdx.x;
  const int bg = blockIdx.y;
  const int t  = threadIdx.x;

  // ---- stage 128 KB, contiguous ----
  {
    const v4u* __restrict__ src =
        reinterpret_cast<const v4u*>(inTg + (size_t)bg * IN_WIDTH * BCHUNK);
    v4u* dst = reinterpret_cast<v4u*>(lds);
#pragma unroll
    for (int i = 0; i < 8; ++i) dst[i * 1024 + t] = src[i * 1024 + t];
  }
  __syncthreads();

  const int wv = t >> 6;
  const int l  = t & 63;
  const int p  = l & 1;                     // batch half (8 of 16)

  v2f a0 = {0.f, 0.f}, a1 = {0.f, 0.f}, a2 = {0.f, 0.f}, a3 = {0.f, 0.f};
  int o;

  if (wv < WL) {
    // =================== LDS leg (R7 pipeline, verbatim) ===================
    o = og * OBLK + wv * 32 + (l >> 1);
    const uint32_t sb = (uint32_t)(size_t)lds + (uint32_t)(p * 16);
    const uint4* __restrict__ pko =
        reinterpret_cast<const uint4*>(pk + (size_t)o * FAN_IN);

#define DSREAD(d, jj) \
  asm volatile("ds_read_b128 %0, %1" : "=v"(d) : "v"(sb + ((jj) << 5)))
#define WAIT4() do { asm volatile("s_waitcnt lgkmcnt(4)" ::: "memory"); \
                     __builtin_amdgcn_sched_barrier(0); } while (0)
#define WAIT0() do { asm volatile("s_waitcnt lgkmcnt(0)" ::: "memory"); \
                     __builtin_amdgcn_sched_barrier(0); } while (0)

    uint4 q0a = pko[0], q0b = pko[1];   // g0
    uint4 q1a = pko[2], q1b = pko[3];   // g1
    uint4 q2a = pko[4], q2b = pko[5];   // g2
    uint4 q3a = pko[6], q3b = pko[7];   // g3

    v4u vA0, vA1, vA2, vA3, vB0, vB1, vB2, vB3;
    uint32_t wA0, wA1, wA2, wA3, wB0, wB1, wB2, wB3;

    DSREAD(vA0, q0a.x); DSREAD(vA1, q0a.z); DSREAD(vA2, q0b.x); DSREAD(vA3, q0b.z);
    wA0 = q0a.y; wA1 = q0a.w; wA2 = q0b.y; wA3 = q0b.w;

#define STEP(Cc, QI0, QI1, QR0, QR1,                                   \
             VC0, VC1, VC2, VC3, WC0, WC1, WC2, WC3,                   \
             VI0, VI1, VI2, VI3, WI0, WI1, WI2, WI3)                   \
  do {                                                                 \
    DSREAD(VI0, QI0.x); DSREAD(VI1, QI0.z);                            \
    DSREAD(VI2, QI1.x); DSREAD(VI3, QI1.z);                            \
    WI0 = QI0.y; WI1 = QI0.w; WI2 = QI1.y; WI3 = QI1.w;                \
    {                                                                  \
      const int gn_ = ((Cc) + 4 > 31) ? 31 : ((Cc) + 4);               \
      QR0 = pko[2 * gn_];                                              \
      QR1 = pko[2 * gn_ + 1];                                          \
    }                                                                  \
    WAIT4();                                                           \
    CONSUME(VC0, WC0); CONSUME(VC1, WC1);                              \
    CONSUME(VC2, WC2); CONSUME(VC3, WC3);                              \
  } while (0)
#define STEP_A(Cc, QI0, QI1, QR0, QR1)                                   \
  STEP(Cc, QI0, QI1, QR0, QR1,                                           \
       vA0, vA1, vA2, vA3, wA0, wA1, wA2, wA3,                           \
       vB0, vB1, vB2, vB3, wB0, wB1, wB2, wB3)
#define STEP_B(Cc, QI0, QI1, QR0, QR1)                                   \
  STEP(Cc, QI0, QI1, QR0, QR1,                                           \
       vB0, vB1, vB2, vB3, wB0, wB1, wB2, wB3,                           \
       vA0, vA1, vA2, vA3, wA0, wA1, wA2, wA3)

#pragma unroll 1
    for (int cb = 0; cb < 28; cb += 4) {
      STEP_A(cb + 0, q1a, q1b, q0a, q0b);
      STEP_B(cb + 1, q2a, q2b, q1a, q1b);
      STEP_A(cb + 2, q3a, q3b, q2a, q2b);
      STEP_B(cb + 3, q0a, q0b, q3a, q3b);
    }
    STEP_A(28, q1a, q1b, q0a, q0b);
    STEP_B(29, q2a, q2b, q1a, q1b);
    STEP_A(30, q3a, q3b, q2a, q2b);
    WAIT0();
    CONSUME(vB0, wB0); CONSUME(vB1, wB1); CONSUME(vB2, wB2); CONSUME(vB3, wB3);
#undef STEP_B
#undef STEP_A
#undef STEP
#undef WAIT4
#undef WAIT0
#undef DSREAD
  } else {
    // =================== L2 leg (global reads of the same slice) ==========
    o = og * OBLK + WL * 32 + (wv - WL) * 32 + (l >> 1);
    const uint16_t* __restrict__ gbase =
        inTg + (size_t)bg * IN_WIDTH * BCHUNK + p * 8;
    const uint4* __restrict__ pko =
        reinterpret_cast<const uint4*>(pk + (size_t)o * FAN_IN);

#define GLD(jj) (*reinterpret_cast<const uint4*>(gbase + (size_t)(jj) * BCHUNK))

    // ping-pong: issue group g+1's 4 loads before consuming group g
    uint4 qa = pko[0], qb = pko[1];
    uint4 va0 = GLD(qa.x), va1 = GLD(qa.z), va2 = GLD(qb.x), va3 = GLD(qb.z);
#pragma unroll 1
    for (int g = 0; g < 31; ++g) {
      const uint4 qn0 = pko[2 * g + 2];
      const uint4 qn1 = pko[2 * g + 3];
      const uint4 vb0 = GLD(qn0.x), vb1 = GLD(qn0.z);
      const uint4 vb2 = GLD(qn1.x), vb3 = GLD(qn1.z);
      CONSUME(va0, qa.y); CONSUME(va1, qa.w);
      CONSUME(va2, qb.y); CONSUME(va3, qb.w);
      qa = qn0; qb = qn1;
      va0 = vb0; va1 = vb1; va2 = vb2; va3 = vb3;
    }
    CONSUME(va0, qa.y); CONSUME(va1, qa.w);
    CONSUME(va2, qb.y); CONSUME(va3, qb.w);
#undef GLD
  }

  const float bz = bias[o];
  const float r[8] = {a0[0], a0[1], a1[0], a1[1], a2[0], a2[1], a3[0], a3[1]};
  // out[b][o], b = bg*16 + p*8 + i
  const size_t obase = (size_t)(bg * BCHUNK + p * 8) * OUT_F + o;
#pragma unroll
  for (int i = 0; i < 8; ++i) out[obase + (size_t)i * OUT_F] = r[i] + bz;
}

extern "C" void kernel_launch(void* const* d_in, const int* in_sizes, int n_in,
                              void* d_out, int out_size, void* d_ws, size_t ws_size,
                              hipStream_t stream) {
  const float* input  = (const float*)d_in[0];   // [512][4096] f32
  const float* weight = (const float*)d_in[1];   // [4096][128] f32
  const float* bias   = (const float*)d_in[2];   // [4096]      f32
  const int*   idx    = (const int*)d_in[3];     // [4096][128] int32
  float* out = (float*)d_out;                    // [512][4096] f32

  // ws: inTg (bf16, 4 MB) | pk (uint2, 4 MB)
  uint16_t* inTg = (uint16_t*)d_ws;
  uint2*    pk   = (uint2*)((char*)d_ws + 4u * 1024 * 1024);

  dim3 tblk(32, 8);
  k_transpose_in<<<dim3(IN_WIDTH / 32, BATCH / 32), tblk, 0, stream>>>(input, inTg);
  k_pack<<<dim3(OUT_F * FAN_IN / 256), dim3(256), 0, stream>>>(idx, weight, pk);
  k_gather_hyb<<<dim3(NOG, NBG), dim3(1024), IN_WIDTH * BCHUNK * 2, stream>>>(
      inTg, pk, bias, out);
}

// Round 10
// 39.660 us; speedup vs baseline: 2.3896x; 1.8354x over previous
//
#include <hip/hip_runtime.h>
#include <hip/hip_bf16.h>

#define BATCH    512
#define IN_WIDTH 4096
#define OUT_F    4096
#define FAN_IN   128

typedef float    v2f __attribute__((ext_vector_type(2)));
typedef uint32_t v4u __attribute__((ext_vector_type(4)));

// ---------------------------------------------------------------------------
// Kernel A: transpose input [BATCH][IN_WIDTH] f32 -> inTf [IN_WIDTH][BATCH]
// bf16 (1 KB rows). 32x32 LDS tile, +1 pad.
// ---------------------------------------------------------------------------
__global__ __launch_bounds__(256) void k_transpose_in(const float* __restrict__ in,
                                                      uint16_t* __restrict__ inTf) {
  __shared__ float tile[32][33];
  const int jt = blockIdx.x * 32;
  const int bt = blockIdx.y * 32;
  const int tx = threadIdx.x;       // 0..31
  const int ty = threadIdx.y;       // 0..7
#pragma unroll
  for (int r = 0; r < 32; r += 8) {
    tile[ty + r][tx] = in[(size_t)(bt + ty + r) * IN_WIDTH + (jt + tx)];
  }
  __syncthreads();
#pragma unroll
  for (int r = 0; r < 32; r += 8) {
    const int b = bt + tx;
    const int j = jt + ty + r;
    __hip_bfloat16 hv = __float2bfloat16(tile[tx][ty + r]);
    inTf[(size_t)j * BATCH + b] = *reinterpret_cast<const uint16_t*>(&hv);
  }
}

// ---------------------------------------------------------------------------
// Kernel B: L2-served gather, wave-uniform j.
// One wave per o (8 waves/block, 512 blocks = 2 blocks/CU).
// Per f: j = idx[o][f] (s_load, uniform), each lane global_load_dwordx4 at
// inTf + j*1024 + lane*16  -> one contiguous 1 KB wave transaction.
// Depth-4 rotation, counted s_waitcnt vmcnt(3). Our asm loads are the only
// vmcnt ops in the loop (idx/weight/bias are scalar lgkm) -> counts are exact.
// ---------------------------------------------------------------------------
__global__ __launch_bounds__(512, 4) void k_gather_l2(const uint16_t* __restrict__ inTf,
                                                      const int* __restrict__ idx,
                                                      const float* __restrict__ weight,
                                                      const float* __restrict__ bias,
                                                      float* __restrict__ outT) {
  const int t    = threadIdx.x;
  const int lane = t & 63;
  const int o    = __builtin_amdgcn_readfirstlane(blockIdx.x * 8 + (t >> 6));

  const int*   __restrict__ idxo = idx + (size_t)o * FAN_IN;
  const float* __restrict__ wo   = weight + (size_t)o * FAN_IN;
  const uint32_t voff = (uint32_t)lane * 16u;

  v2f a0 = {0.f, 0.f}, a1 = {0.f, 0.f}, a2 = {0.f, 0.f}, a3 = {0.f, 0.f};

#define GISSUE(S, jj)                                                        \
  do {                                                                       \
    const uint32_t va_ = ((uint32_t)(jj) << 10) + voff;                      \
    asm volatile("global_load_dwordx4 %0, %1, %2"                            \
                 : "=&v"(S) : "v"(va_), "s"(inTf));                          \
  } while (0)

#define WAITV(n) do { asm volatile("s_waitcnt vmcnt(" #n ")" ::: "memory");  \
                      __builtin_amdgcn_sched_barrier(0); } while (0)

#define CONSUMEF(v, wf)                                                \
  do {                                                                 \
    v2f w2_; w2_[0] = (wf); w2_[1] = (wf);                             \
    v2f x0_, x1_, x2_, x3_;                                            \
    x0_[0] = __uint_as_float((v)[0] << 16);                            \
    x0_[1] = __uint_as_float((v)[0] & 0xffff0000u);                    \
    x1_[0] = __uint_as_float((v)[1] << 16);                            \
    x1_[1] = __uint_as_float((v)[1] & 0xffff0000u);                    \
    x2_[0] = __uint_as_float((v)[2] << 16);                            \
    x2_[1] = __uint_as_float((v)[2] & 0xffff0000u);                    \
    x3_[0] = __uint_as_float((v)[3] << 16);                            \
    x3_[1] = __uint_as_float((v)[3] & 0xffff0000u);                    \
    a0 += x0_ * w2_; a1 += x1_ * w2_; a2 += x2_ * w2_; a3 += x3_ * w2_;\
  } while (0)

  v4u S0, S1, S2, S3;
  int   j0 = idxo[0], j1 = idxo[1], j2 = idxo[2], j3 = idxo[3];
  float w0 = wo[0],   w1 = wo[1],   w2 = wo[2],   w3 = wo[3];

  GISSUE(S0, j0); GISSUE(S1, j1); GISSUE(S2, j2); GISSUE(S3, j3);

#pragma unroll 1
  for (int c = 0; c < 124; c += 4) {
    const int   jn0 = idxo[c + 4], jn1 = idxo[c + 5];
    const int   jn2 = idxo[c + 6], jn3 = idxo[c + 7];
    const float wn0 = wo[c + 4],   wn1 = wo[c + 5];
    const float wn2 = wo[c + 6],   wn3 = wo[c + 7];
    WAITV(3); CONSUMEF(S0, w0); GISSUE(S0, jn0); w0 = wn0;
    WAITV(3); CONSUMEF(S1, w1); GISSUE(S1, jn1); w1 = wn1;
    WAITV(3); CONSUMEF(S2, w2); GISSUE(S2, jn2); w2 = wn2;
    WAITV(3); CONSUMEF(S3, w3); GISSUE(S3, jn3); w3 = wn3;
  }
  WAITV(3); CONSUMEF(S0, w0);
  WAITV(2); CONSUMEF(S1, w1);
  WAITV(1); CONSUMEF(S2, w2);
  WAITV(0); CONSUMEF(S3, w3);

  const float bz = bias[o];
  float4 r0 = make_float4(a0[0] + bz, a0[1] + bz, a1[0] + bz, a1[1] + bz);
  float4 r1 = make_float4(a2[0] + bz, a2[1] + bz, a3[0] + bz, a3[1] + bz);
  float4* dst = reinterpret_cast<float4*>(outT + (size_t)o * BATCH + lane * 8);
  dst[0] = r0;
  dst[1] = r1;

#undef CONSUMEF
#undef WAITV
#undef GISSUE
}

// ---------------------------------------------------------------------------
// Kernel C: transpose outT [OUT_F][BATCH] f32 -> out [BATCH][OUT_F] f32
// ---------------------------------------------------------------------------
__global__ __launch_bounds__(256) void k_transpose_out(const float* __restrict__ outT,
                                                       float* __restrict__ out) {
  __shared__ float tile[32][33];
  const int ot = blockIdx.x * 32;
  const int bt = blockIdx.y * 32;
  const int tx = threadIdx.x;
  const int ty = threadIdx.y;
#pragma unroll
  for (int r = 0; r < 32; r += 8) {
    tile[ty + r][tx] = outT[(size_t)(ot + ty + r) * BATCH + (bt + tx)];
  }
  __syncthreads();
#pragma unroll
  for (int r = 0; r < 32; r += 8) {
    out[(size_t)(bt + ty + r) * OUT_F + (ot + tx)] = tile[tx][ty + r];
  }
}

extern "C" void kernel_launch(void* const* d_in, const int* in_sizes, int n_in,
                              void* d_out, int out_size, void* d_ws, size_t ws_size,
                              hipStream_t stream) {
  const float* input  = (const float*)d_in[0];   // [512][4096] f32
  const float* weight = (const float*)d_in[1];   // [4096][128] f32
  const float* bias   = (const float*)d_in[2];   // [4096]      f32
  const int*   idx    = (const int*)d_in[3];     // [4096][128] int32
  float* out = (float*)d_out;                    // [512][4096] f32

  // ws: inTf (bf16, 4 MB) | outT (f32, 8 MB)
  uint16_t* inTf = (uint16_t*)d_ws;
  float*    outT = (float*)((char*)d_ws + 4u * 1024 * 1024);

  dim3 tblk(32, 8);
  k_transpose_in<<<dim3(IN_WIDTH / 32, BATCH / 32), tblk, 0, stream>>>(input, inTf);
  k_gather_l2<<<dim3(OUT_F / 8), dim3(512), 0, stream>>>(inTf, idx, weight, bias, outT);
  k_transpose_out<<<dim3(OUT_F / 32, BATCH / 32), tblk, 0, stream>>>(outT, out);
}